// Round 1
// baseline (307.928 us; speedup 1.0000x reference)
//
#include <hip/hip_runtime.h>
#include <math.h>

// ForwardDiffusion: x_{t} = a*x_{t-1} + c*z_t, a = 1-THETA*DT, c = SIGMA0*sqrt(DT).
// Noise is batch-independent => closed form x_t[b,l] = a^t * x0[b,l] + c * S_t[l]
// with S_t[l] = a*S_{t-1}[l] + z_t[l] computed once (not per-batch).
//
// ws layout (floats): S[STEPS*LEN] local-scan values | carry[NCHUNK*LEN] | apow[STEPS]
// total ~4.4 MB.

namespace {
constexpr int LEN    = 1024;
constexpr int BATCH  = 64;
constexpr int STEPS  = 1000;
constexpr int NST    = 999;               // steps with noise
constexpr int CHUNK  = 16;
constexpr int NCHUNK = (NST + CHUNK - 1) / CHUNK;  // 63
constexpr float THETA = 1.0f;
constexpr float DT    = 0.001f;
}

// Kernel 1: per-chunk local scans (carry-in = 0). S[t][l] holds the local scan L_t.
// Block g handles t in [g*CHUNK+1, min((g+1)*CHUNK, NST)]. Block 0 zeroes row t=0.
__global__ __launch_bounds__(1024) void k_partial(const float* __restrict__ noise,
                                                  float* __restrict__ S) {
    const int l = threadIdx.x;
    const int g = blockIdx.x;
    const float a = 1.0f - THETA * DT;
    if (g == 0) S[l] = 0.0f;                 // t = 0 row: S_0 = 0
    const int t0 = g * CHUNK + 1;
    const int t1 = min((g + 1) * CHUNK, NST);
    float acc = 0.0f;
    for (int t = t0; t <= t1; ++t) {
        acc = a * acc + noise[(t - 1) * LEN + l];
        S[t * LEN + l] = acc;
    }
}

// Kernel 2: sequential combine of chunk carries (63 iters, trivial) + a^t table.
// carry[g][l] = S_{g*CHUNK}[l]  (the carry entering chunk g; carry[0] = 0).
__global__ __launch_bounds__(1024) void k_combine(const float* __restrict__ S,
                                                  float* __restrict__ carry,
                                                  float* __restrict__ apow) {
    const int l = threadIdx.x;
    const float a = 1.0f - THETA * DT;
    if (l < STEPS) apow[l] = powf(a, (float)l);
    __syncthreads();
    float cr = 0.0f;
    for (int g = 0; g < NCHUNK; ++g) {
        carry[g * LEN + l] = cr;
        const int t1  = min((g + 1) * CHUNK, NST);
        const int len = t1 - g * CHUNK;
        cr = apow[len] * cr + S[t1 * LEN + l];   // S_{t1} = L_{t1} + a^len * S_{g*CHUNK}
    }
}

// Kernel 3: emit out[b][t][l] = a^t * x0[b,l] + c * (L_t[l] + a^{t-g*CHUNK} * carry[g][l]).
// One block per (b,t) row, 256 threads x float4. x0/S/carry rows are cache-resident;
// this kernel is a pure 262 MB HBM write stream.
__global__ __launch_bounds__(256) void k_emit(const float* __restrict__ x0,
                                              const float* __restrict__ S,
                                              const float* __restrict__ carry,
                                              const float* __restrict__ apow,
                                              float* __restrict__ out) {
    const int blk = blockIdx.x;              // b*STEPS + t
    const int b = blk / STEPS;
    const int t = blk - b * STEPS;
    const int g = (t - 1) / CHUNK;           // t=0 -> 0 (carry row 0 is zeros, safe)
    const int tloc = t - g * CHUNK;
    const float ap = apow[t];
    const float al = apow[tloc];
    const float c = 0.5f * sqrtf(DT);
    const int l4 = threadIdx.x;
    const float4 x  = ((const float4*)(x0 + b * LEN))[l4];
    const float4 s  = ((const float4*)(S + t * LEN))[l4];
    const float4 cr = ((const float4*)(carry + g * LEN))[l4];
    float4 o;
    o.x = ap * x.x + c * (s.x + al * cr.x);
    o.y = ap * x.y + c * (s.y + al * cr.y);
    o.z = ap * x.z + c * (s.z + al * cr.z);
    o.w = ap * x.w + c * (s.w + al * cr.w);
    ((float4*)(out + (size_t)blk * LEN))[l4] = o;
}

extern "C" void kernel_launch(void* const* d_in, const int* in_sizes, int n_in,
                              void* d_out, int out_size, void* d_ws, size_t ws_size,
                              hipStream_t stream) {
    const float* x     = (const float*)d_in[0];   // (64, 1024) fp32
    const float* noise = (const float*)d_in[1];   // (999, 1024) fp32
    float* out = (float*)d_out;                   // (64, 1000, 1024) fp32
    float* ws  = (float*)d_ws;

    float* S     = ws;                      // STEPS*LEN floats
    float* carry = S + STEPS * LEN;         // NCHUNK*LEN floats
    float* apow  = carry + NCHUNK * LEN;    // STEPS floats

    hipLaunchKernelGGL(k_partial, dim3(NCHUNK), dim3(1024), 0, stream, noise, S);
    hipLaunchKernelGGL(k_combine, dim3(1), dim3(1024), 0, stream, S, carry, apow);
    hipLaunchKernelGGL(k_emit, dim3(BATCH * STEPS), dim3(256), 0, stream,
                       x, S, carry, apow, out);
}

// Round 3
// 271.937 us; speedup vs baseline: 1.1323x; 1.1323x over previous
//
#include <hip/hip_runtime.h>
#include <math.h>

// ForwardDiffusion: x_t = a*x_{t-1} + c*z_t, a = 1-THETA*DT, c = SIGMA0*sqrt(DT).
// Noise is batch-independent => closed form x_t[b,l] = a^t * x0[b,l] + c * S_t[l],
// S_t[l] = a*S_{t-1}[l] + z_t[l] (single (999,1024) scan, no per-batch scan).
//
// ws layout (floats): S[STEPS*LEN] | carry[NCHUNK*LEN] | apow[STEPS]

namespace {
constexpr int LEN    = 1024;
constexpr int BATCH  = 64;
constexpr int STEPS  = 1000;
constexpr int NST    = 999;
constexpr int CHUNK  = 16;
constexpr int NCHUNK = (NST + CHUNK - 1) / CHUNK;  // 63
constexpr float THETA = 1.0f;
constexpr float DT    = 0.001f;
typedef float f32x4 __attribute__((ext_vector_type(4)));  // native vector: OK for nontemporal builtins
}

// Kernel 1: per-chunk local scans, carry-in 0. grid (NCHUNK, 4) x 256 threads:
// 252 blocks spread across CUs. Block (g, y) handles lanes [y*256, y*256+256)
// for t in [g*CHUNK+1, min((g+1)*CHUNK, NST)]. g==0 also zeroes the t=0 row.
__global__ __launch_bounds__(256) void k_partial(const float* __restrict__ noise,
                                                 float* __restrict__ S) {
    const int l = blockIdx.y * 256 + threadIdx.x;
    const int g = blockIdx.x;
    const float a = 1.0f - THETA * DT;
    if (g == 0) S[l] = 0.0f;
    const int t0 = g * CHUNK + 1;
    const int t1 = min((g + 1) * CHUNK, NST);
    float acc = 0.0f;
    #pragma unroll
    for (int t = t0; t <= t1; ++t) {
        acc = a * acc + noise[(t - 1) * LEN + l];
        S[t * LEN + l] = acc;
    }
}

// Kernel 2: combine chunk carries. grid (4) x 256 threads. The 63 S-loads are
// independent of the serial FMA chain -> prefetch all into registers first
// (latency paid once, not 63x). Also builds the a^t table.
__global__ __launch_bounds__(256) void k_combine(const float* __restrict__ S,
                                                 float* __restrict__ carry,
                                                 float* __restrict__ apow) {
    const int l = blockIdx.x * 256 + threadIdx.x;
    const float a = 1.0f - THETA * DT;
    if (l < STEPS) apow[l] = powf(a, (float)l);

    float vals[NCHUNK];
    #pragma unroll
    for (int g = 0; g < NCHUNK; ++g) {
        const int t1 = min((g + 1) * CHUNK, NST);
        vals[g] = S[t1 * LEN + l];           // independent loads, pipelined
    }
    // a^CHUNK; the last (short) chunk's carry-out is never consumed, so constant is safe.
    const float a16 = 0.98411684f;           // (1-0.001)^16
    float cr = 0.0f;
    #pragma unroll
    for (int g = 0; g < NCHUNK; ++g) {
        carry[g * LEN + l] = cr;
        cr = a16 * cr + vals[g];
    }
}

// Kernel 3: out[b][t][l] = a^t * x0[b,l] + c*S_row[l] + (c*a^tloc)*carry[g][l].
// grid (BATCH, STEPS): 64 consecutive blocks share one S row (tight L2 reuse window).
// Non-temporal stores keep the 262 MB write stream from evicting S/x0/carry from L2.
__global__ __launch_bounds__(256) void k_emit(const float* __restrict__ x0,
                                              const float* __restrict__ S,
                                              const float* __restrict__ carry,
                                              const float* __restrict__ apow,
                                              float* __restrict__ out) {
    const int b = blockIdx.x;
    const int t = blockIdx.y;
    const int g = (max(t, 1) - 1) >> 4;      // t=0 -> g=0 (carry row 0 is zeros)
    const int tloc = t - g * CHUNK;
    const float c  = 0.5f * sqrtf(DT);
    const float ap = apow[t];
    const float cal = c * apow[tloc];
    const int l4 = threadIdx.x;
    const f32x4 x  = ((const f32x4*)(x0 + b * LEN))[l4];
    const f32x4 s  = ((const f32x4*)(S + t * LEN))[l4];
    const f32x4 cr = ((const f32x4*)(carry + g * LEN))[l4];
    f32x4 o = ap * x + c * s + cal * cr;
    f32x4* dst = (f32x4*)(out + ((size_t)b * STEPS + t) * LEN) + l4;
    __builtin_nontemporal_store(o, dst);
}

extern "C" void kernel_launch(void* const* d_in, const int* in_sizes, int n_in,
                              void* d_out, int out_size, void* d_ws, size_t ws_size,
                              hipStream_t stream) {
    const float* x     = (const float*)d_in[0];   // (64, 1024) fp32
    const float* noise = (const float*)d_in[1];   // (999, 1024) fp32
    float* out = (float*)d_out;                   // (64, 1000, 1024) fp32
    float* ws  = (float*)d_ws;

    float* S     = ws;                      // STEPS*LEN
    float* carry = S + STEPS * LEN;         // NCHUNK*LEN
    float* apow  = carry + NCHUNK * LEN;    // STEPS

    hipLaunchKernelGGL(k_partial, dim3(NCHUNK, 4), dim3(256), 0, stream, noise, S);
    hipLaunchKernelGGL(k_combine, dim3(4), dim3(256), 0, stream, S, carry, apow);
    hipLaunchKernelGGL(k_emit, dim3(BATCH, STEPS), dim3(256), 0, stream,
                       x, S, carry, apow, out);
}